// Round 1
// baseline (367.683 us; speedup 1.0000x reference)
//
#include <hip/hip_runtime.h>
#include <hip/hip_bf16.h>

// Problem constants (B=8, S=8192, K=1024, N=1024, G=128)
#define M_DIM 65536
#define K_DIM 1024
#define N_DIM 1024
#define NGRP  8

#define BM 128
#define BN 128
#define BK 32
#define NKT (K_DIM / BK)

typedef float f32x4 __attribute__((ext_vector_type(4)));
typedef __bf16 bf16x8 __attribute__((ext_vector_type(8)));

// ---------------- prep: dequant W -> bf16 [N][K], bias -> f32 ----------------
__global__ void prep_kernel(const int* __restrict__ w_q,
                            const float* __restrict__ w_scale,
                            const int* __restrict__ w_zp,
                            const int* __restrict__ bias_q,
                            const float* __restrict__ bias_scale,
                            __hip_bfloat16* __restrict__ Wb,
                            float* __restrict__ bias_f) {
    const int n = blockIdx.x;       // 0..1023
    const int t = threadIdx.x;      // 0..255
    const int k0 = t * 4;
    const int g = k0 >> 7;          // group of 128
    const float s  = w_scale[n * NGRP + g];
    const float zp = (float)w_zp[n * NGRP + g];
    const int4 wq = *reinterpret_cast<const int4*>(w_q + (size_t)n * K_DIM + k0);
    union { ushort4 u; __hip_bfloat16 h[4]; } pk;
    pk.h[0] = __float2bfloat16(((float)wq.x - zp) * s);
    pk.h[1] = __float2bfloat16(((float)wq.y - zp) * s);
    pk.h[2] = __float2bfloat16(((float)wq.z - zp) * s);
    pk.h[3] = __float2bfloat16(((float)wq.w - zp) * s);
    *reinterpret_cast<ushort4*>(Wb + (size_t)n * K_DIM + k0) = pk.u;
    if (t == 0) bias_f[n] = ((float)bias_q[n] - 128.0f) * bias_scale[n];
}

// ---------------- fused fake-quant GEMM ----------------
__global__ __launch_bounds__(256) void gemm_kernel(
    const float* __restrict__ x,
    const __hip_bfloat16* __restrict__ Wb,
    const float* __restrict__ bias_f,
    const float* __restrict__ in_scale_p, const int* __restrict__ in_zp_p,
    const float* __restrict__ out_scale_p, const int* __restrict__ out_zp_p,
    float* __restrict__ out)
{
    __shared__ __align__(16) __hip_bfloat16 As[2][BM][BK];
    __shared__ __align__(16) __hip_bfloat16 Bs[2][BN][BK];

    const int t = threadIdx.x;
    const int bid = blockIdx.x;
    const int nt = bid & 7;         // 8 n-tiles: consecutive blocks share x panel
    const int mt = bid >> 3;
    const int m0 = mt * BM;
    const int n0 = nt * BN;

    const int wid = t >> 6;
    const int lane = t & 63;
    const int wr = wid >> 1, wc = wid & 1;   // 2x2 waves, each 64x64
    const int lrow = lane & 15;
    const int kslot = lane >> 4;             // k-chunk: kslot*8

    const float in_s = in_scale_p[0];
    const float in_inv = 1.0f / in_s;
    const float izp = (float)in_zp_p[0];

    // ---- staging helpers ----
    auto stageB = [&](int b, int kt) {
        const int k0 = kt * BK;
#pragma unroll
        for (int j = 0; j < 2; ++j) {
            const int c = (wid * 2 + j) * 64 + lane;   // 16B chunk id, 0..511
            const int row = c >> 2;                     // 4 chunks per 64B row
            const int slot = c & 3;
            const __hip_bfloat16* src = Wb + (size_t)(n0 + row) * K_DIM + k0 + slot * 8;
            __builtin_amdgcn_global_load_lds(
                (const __attribute__((address_space(1))) void*)src,
                (__attribute__((address_space(3))) void*)((char*)&Bs[b][0][0] + (wid * 2 + j) * 1024),
                16, 0, 0);
        }
    };
    auto stageA = [&](int b, int kt) {
        const int k0 = kt * BK;
#pragma unroll
        for (int i = 0; i < 4; ++i) {
            const int c = t + 256 * i;                  // float4 chunk id, 0..1023
            const int row = c >> 3;                     // 8 float4 per 128B row
            const int slot = c & 7;
            const float4 v = *reinterpret_cast<const float4*>(
                x + (size_t)(m0 + row) * K_DIM + k0 + slot * 4);
            float vv[4] = {v.x, v.y, v.z, v.w};
            union { ushort4 u; __hip_bfloat16 h[4]; } pk;
#pragma unroll
            for (int e = 0; e < 4; ++e) {
                float q = rintf(vv[e] * in_inv) + izp;          // RNE matches jnp.round
                q = fminf(fmaxf(q, -128.0f), 127.0f);
                pk.h[e] = __float2bfloat16((q - izp) * in_s);
            }
            *reinterpret_cast<ushort4*>(&As[b][row][slot * 4]) = pk.u;
        }
    };

    f32x4 acc[4][4];
#pragma unroll
    for (int mi = 0; mi < 4; ++mi)
#pragma unroll
        for (int ni = 0; ni < 4; ++ni)
            acc[mi][ni] = (f32x4){0.f, 0.f, 0.f, 0.f};

    stageB(0, 0);
    stageA(0, 0);
    __syncthreads();

    for (int kt = 0; kt < NKT; ++kt) {
        const int buf = kt & 1;
        if (kt + 1 < NKT) {
            stageB(buf ^ 1, kt + 1);
            stageA(buf ^ 1, kt + 1);
        }
        bf16x8 af[4], bfr[4];
#pragma unroll
        for (int mi = 0; mi < 4; ++mi)
            af[mi] = *reinterpret_cast<const bf16x8*>(&As[buf][wr * 64 + mi * 16 + lrow][kslot * 8]);
#pragma unroll
        for (int ni = 0; ni < 4; ++ni)
            bfr[ni] = *reinterpret_cast<const bf16x8*>(&Bs[buf][wc * 64 + ni * 16 + lrow][kslot * 8]);
#pragma unroll
        for (int mi = 0; mi < 4; ++mi)
#pragma unroll
            for (int ni = 0; ni < 4; ++ni)
                acc[mi][ni] = __builtin_amdgcn_mfma_f32_16x16x32_bf16(af[mi], bfr[ni], acc[mi][ni], 0, 0, 0);
        __syncthreads();
    }

    // ---- epilogue: bias + output fake-quant ----
    const float out_s = out_scale_p[0];
    const float out_inv = 1.0f / out_s;
    const float ozp = (float)out_zp_p[0];
    const int col = lane & 15;
    const int rgrp = lane >> 4;
#pragma unroll
    for (int ni = 0; ni < 4; ++ni) {
        const int n = n0 + wc * 64 + ni * 16 + col;
        const float bv = bias_f[n];
#pragma unroll
        for (int mi = 0; mi < 4; ++mi) {
#pragma unroll
            for (int j = 0; j < 4; ++j) {
                const int m = m0 + wr * 64 + mi * 16 + rgrp * 4 + j;
                float v = acc[mi][ni][j] + bv;
                float q = rintf(v * out_inv) + ozp;
                q = fminf(fmaxf(q, -128.0f), 127.0f);
                out[(size_t)m * N_DIM + n] = (q - ozp) * out_s;
            }
        }
    }
}

extern "C" void kernel_launch(void* const* d_in, const int* in_sizes, int n_in,
                              void* d_out, int out_size, void* d_ws, size_t ws_size,
                              hipStream_t stream) {
    const float* x          = (const float*)d_in[0];
    const int*   w_q        = (const int*)d_in[1];
    const float* w_scale    = (const float*)d_in[2];
    const int*   w_zp       = (const int*)d_in[3];
    const int*   bias_q     = (const int*)d_in[4];
    const float* bias_scale = (const float*)d_in[5];
    const float* in_scale   = (const float*)d_in[6];
    const int*   in_zp      = (const int*)d_in[7];
    const float* out_scale  = (const float*)d_in[8];
    const int*   out_zp     = (const int*)d_in[9];

    __hip_bfloat16* Wb = (__hip_bfloat16*)d_ws;
    float* bias_f = (float*)((char*)d_ws + (size_t)N_DIM * K_DIM * sizeof(__hip_bfloat16));

    prep_kernel<<<N_DIM, 256, 0, stream>>>(w_q, w_scale, w_zp, bias_q, bias_scale, Wb, bias_f);

    const int grid = (M_DIM / BM) * (N_DIM / BN);   // 512 * 8 = 4096
    gemm_kernel<<<grid, 256, 0, stream>>>(x, Wb, bias_f, in_scale, in_zp,
                                          out_scale, out_zp, (float*)d_out);
}

// Round 2
// 320.691 us; speedup vs baseline: 1.1465x; 1.1465x over previous
//
#include <hip/hip_runtime.h>
#include <hip/hip_bf16.h>

// Problem constants (B=8, S=8192, K=1024, N=1024, G=128)
#define M_DIM 65536
#define K_DIM 1024
#define N_DIM 1024
#define NGRP  8

#define BM 128
#define BN 128
#define BK 32
#define NKT (K_DIM / BK)

typedef float f32x4 __attribute__((ext_vector_type(4)));
typedef __bf16 bf16x8 __attribute__((ext_vector_type(8)));

// ---------------- prep: dequant W -> bf16 [N][K], bias -> f32 ----------------
__global__ void prep_kernel(const int* __restrict__ w_q,
                            const float* __restrict__ w_scale,
                            const int* __restrict__ w_zp,
                            const int* __restrict__ bias_q,
                            const float* __restrict__ bias_scale,
                            __hip_bfloat16* __restrict__ Wb,
                            float* __restrict__ bias_f) {
    const int n = blockIdx.x;       // 0..1023
    const int t = threadIdx.x;      // 0..255
    const int k0 = t * 4;
    const int g = k0 >> 7;          // group of 128
    const float s  = w_scale[n * NGRP + g];
    const float zp = (float)w_zp[n * NGRP + g];
    const int4 wq = *reinterpret_cast<const int4*>(w_q + (size_t)n * K_DIM + k0);
    union { ushort4 u; __hip_bfloat16 h[4]; } pk;
    pk.h[0] = __float2bfloat16(((float)wq.x - zp) * s);
    pk.h[1] = __float2bfloat16(((float)wq.y - zp) * s);
    pk.h[2] = __float2bfloat16(((float)wq.z - zp) * s);
    pk.h[3] = __float2bfloat16(((float)wq.w - zp) * s);
    *reinterpret_cast<ushort4*>(Wb + (size_t)n * K_DIM + k0) = pk.u;
    if (t == 0) bias_f[n] = ((float)bias_q[n] - 128.0f) * bias_scale[n];
}

// ---------------- prep: fake-quant x -> bf16 [M][K] ----------------
__global__ __launch_bounds__(256) void prep_x_kernel(
    const float* __restrict__ x,
    const float* __restrict__ in_scale_p, const int* __restrict__ in_zp_p,
    __hip_bfloat16* __restrict__ Xq)
{
    const float s = in_scale_p[0];
    const float inv = 1.0f / s;
    const float zp = (float)in_zp_p[0];
    const size_t i = ((size_t)blockIdx.x * 256 + threadIdx.x) * 8;
    const float4 v0 = *reinterpret_cast<const float4*>(x + i);
    const float4 v1 = *reinterpret_cast<const float4*>(x + i + 4);
    float vv[8] = {v0.x, v0.y, v0.z, v0.w, v1.x, v1.y, v1.z, v1.w};
    union { uint4 u; __hip_bfloat16 h[8]; } pk;
#pragma unroll
    for (int e = 0; e < 8; ++e) {
        float q = rintf(vv[e] * inv) + zp;       // RNE matches jnp.round
        q = fminf(fmaxf(q, -128.0f), 127.0f);
        pk.h[e] = __float2bfloat16((q - zp) * s);
    }
    *reinterpret_cast<uint4*>(Xq + i) = pk.u;
}

// ---------------- main GEMM: A,B both bf16 via global_load_lds, swizzled LDS ----------------
__global__ __launch_bounds__(256) void gemm_lds_kernel(
    const __hip_bfloat16* __restrict__ Xq,
    const __hip_bfloat16* __restrict__ Wb,
    const float* __restrict__ bias_f,
    const float* __restrict__ out_scale_p, const int* __restrict__ out_zp_p,
    float* __restrict__ out)
{
    __shared__ __align__(16) __hip_bfloat16 As[2][BM * BK];
    __shared__ __align__(16) __hip_bfloat16 Bs[2][BN * BK];

    const int t = threadIdx.x;
    // bijective XCD swizzle: grid=4096, 8 XCDs, 512 tiles/XCD
    const int bid = (blockIdx.x & 7) * 512 + (blockIdx.x >> 3);
    const int nt = bid & 7;
    const int mt = bid >> 3;
    const int m0 = mt * BM;
    const int n0 = nt * BN;

    const int wid = t >> 6;
    const int lane = t & 63;
    const int wr = wid >> 1, wc = wid & 1;   // 2x2 waves, each 64x64
    const int lrow = lane & 15;
    const int kslot = lane >> 4;             // logical k-chunk (8 bf16 each)
    const int swsel = (lrow >> 1) & 3;       // swizzle selector (row-base is mult of 16)
    const int koff = ((kslot ^ swsel) << 4); // physical byte offset of this lane's k-chunk

    // stage one 128x32 bf16 tile via global_load_lds, pre-swizzled source (rule #21)
    auto stage = [&](const __hip_bfloat16* src0, __hip_bfloat16* dst, int kt) {
        const int k0 = kt * BK;
#pragma unroll
        for (int j = 0; j < 2; ++j) {
            const int c = j * 256 + t;            // 16B chunk id, 0..511
            const int r = c >> 2;                 // LDS row (64B rows, 4 chunks)
            const int sl = (c & 3) ^ ((r >> 1) & 3);  // logical k-slot for this phys slot
            const __hip_bfloat16* src = src0 + (size_t)r * K_DIM + k0 + sl * 8;
            __builtin_amdgcn_global_load_lds(
                (const __attribute__((address_space(1))) void*)src,
                (__attribute__((address_space(3))) void*)((char*)dst + (j * 256 + (t & 192)) * 16),
                16, 0, 0);
        }
    };

    f32x4 acc[4][4];
#pragma unroll
    for (int mi = 0; mi < 4; ++mi)
#pragma unroll
        for (int ni = 0; ni < 4; ++ni)
            acc[mi][ni] = (f32x4){0.f, 0.f, 0.f, 0.f};

    const __hip_bfloat16* Abase = Xq + (size_t)m0 * K_DIM;
    const __hip_bfloat16* Bbase = Wb + (size_t)n0 * K_DIM;

    stage(Abase, &As[0][0], 0);
    stage(Bbase, &Bs[0][0], 0);
    __syncthreads();

    for (int kt = 0; kt < NKT; ++kt) {
        const int buf = kt & 1;
        if (kt + 1 < NKT) {
            stage(Abase, &As[buf ^ 1][0], kt + 1);
            stage(Bbase, &Bs[buf ^ 1][0], kt + 1);
        }
        const char* Ab = (const char*)&As[buf][0];
        const char* Bb = (const char*)&Bs[buf][0];
        bf16x8 af[4], bfr[4];
#pragma unroll
        for (int mi = 0; mi < 4; ++mi) {
            const int row = wr * 64 + mi * 16 + lrow;
            af[mi] = *reinterpret_cast<const bf16x8*>(Ab + row * 64 + koff);
        }
#pragma unroll
        for (int ni = 0; ni < 4; ++ni) {
            const int row = wc * 64 + ni * 16 + lrow;
            bfr[ni] = *reinterpret_cast<const bf16x8*>(Bb + row * 64 + koff);
        }
#pragma unroll
        for (int mi = 0; mi < 4; ++mi)
#pragma unroll
            for (int ni = 0; ni < 4; ++ni)
                acc[mi][ni] = __builtin_amdgcn_mfma_f32_16x16x32_bf16(af[mi], bfr[ni], acc[mi][ni], 0, 0, 0);
        __syncthreads();
    }

    // ---- epilogue: bias + output fake-quant ----
    const float out_s = out_scale_p[0];
    const float out_inv = 1.0f / out_s;
    const float ozp = (float)out_zp_p[0];
    const int col = lane & 15;
    const int rgrp = lane >> 4;
#pragma unroll
    for (int ni = 0; ni < 4; ++ni) {
        const int n = n0 + wc * 64 + ni * 16 + col;
        const float bv = bias_f[n];
#pragma unroll
        for (int mi = 0; mi < 4; ++mi) {
#pragma unroll
            for (int j = 0; j < 4; ++j) {
                const int m = m0 + wr * 64 + mi * 16 + rgrp * 4 + j;
                float v = acc[mi][ni][j] + bv;
                float q = rintf(v * out_inv) + ozp;
                q = fminf(fmaxf(q, -128.0f), 127.0f);
                out[(size_t)m * N_DIM + n] = (q - ozp) * out_s;
            }
        }
    }
}

// ---------------- fallback (round-1): fused quant in A-staging, f32 x ----------------
__global__ __launch_bounds__(256) void gemm_fused_kernel(
    const float* __restrict__ x,
    const __hip_bfloat16* __restrict__ Wb,
    const float* __restrict__ bias_f,
    const float* __restrict__ in_scale_p, const int* __restrict__ in_zp_p,
    const float* __restrict__ out_scale_p, const int* __restrict__ out_zp_p,
    float* __restrict__ out)
{
    __shared__ __align__(16) __hip_bfloat16 As[2][BM][BK];
    __shared__ __align__(16) __hip_bfloat16 Bs[2][BN][BK];

    const int t = threadIdx.x;
    const int bid = blockIdx.x;
    const int nt = bid & 7;
    const int mt = bid >> 3;
    const int m0 = mt * BM;
    const int n0 = nt * BN;

    const int wid = t >> 6;
    const int lane = t & 63;
    const int wr = wid >> 1, wc = wid & 1;
    const int lrow = lane & 15;
    const int kslot = lane >> 4;

    const float in_s = in_scale_p[0];
    const float in_inv = 1.0f / in_s;
    const float izp = (float)in_zp_p[0];

    auto stageB = [&](int b, int kt) {
        const int k0 = kt * BK;
#pragma unroll
        for (int j = 0; j < 2; ++j) {
            const int c = (wid * 2 + j) * 64 + lane;
            const int row = c >> 2;
            const int slot = c & 3;
            const __hip_bfloat16* src = Wb + (size_t)(n0 + row) * K_DIM + k0 + slot * 8;
            __builtin_amdgcn_global_load_lds(
                (const __attribute__((address_space(1))) void*)src,
                (__attribute__((address_space(3))) void*)((char*)&Bs[b][0][0] + (wid * 2 + j) * 1024),
                16, 0, 0);
        }
    };
    auto stageA = [&](int b, int kt) {
        const int k0 = kt * BK;
#pragma unroll
        for (int i = 0; i < 4; ++i) {
            const int c = t + 256 * i;
            const int row = c >> 3;
            const int slot = c & 7;
            const float4 v = *reinterpret_cast<const float4*>(
                x + (size_t)(m0 + row) * K_DIM + k0 + slot * 4);
            float vv[4] = {v.x, v.y, v.z, v.w};
            union { ushort4 u; __hip_bfloat16 h[4]; } pk;
#pragma unroll
            for (int e = 0; e < 4; ++e) {
                float q = rintf(vv[e] * in_inv) + izp;
                q = fminf(fmaxf(q, -128.0f), 127.0f);
                pk.h[e] = __float2bfloat16((q - izp) * in_s);
            }
            *reinterpret_cast<ushort4*>(&As[b][row][slot * 4]) = pk.u;
        }
    };

    f32x4 acc[4][4];
#pragma unroll
    for (int mi = 0; mi < 4; ++mi)
#pragma unroll
        for (int ni = 0; ni < 4; ++ni)
            acc[mi][ni] = (f32x4){0.f, 0.f, 0.f, 0.f};

    stageB(0, 0);
    stageA(0, 0);
    __syncthreads();

    for (int kt = 0; kt < NKT; ++kt) {
        const int buf = kt & 1;
        if (kt + 1 < NKT) {
            stageB(buf ^ 1, kt + 1);
            stageA(buf ^ 1, kt + 1);
        }
        bf16x8 af[4], bfr[4];
#pragma unroll
        for (int mi = 0; mi < 4; ++mi)
            af[mi] = *reinterpret_cast<const bf16x8*>(&As[buf][wr * 64 + mi * 16 + lrow][kslot * 8]);
#pragma unroll
        for (int ni = 0; ni < 4; ++ni)
            bfr[ni] = *reinterpret_cast<const bf16x8*>(&Bs[buf][wc * 64 + ni * 16 + lrow][kslot * 8]);
#pragma unroll
        for (int mi = 0; mi < 4; ++mi)
#pragma unroll
            for (int ni = 0; ni < 4; ++ni)
                acc[mi][ni] = __builtin_amdgcn_mfma_f32_16x16x32_bf16(af[mi], bfr[ni], acc[mi][ni], 0, 0, 0);
        __syncthreads();
    }

    const float out_s = out_scale_p[0];
    const float out_inv = 1.0f / out_s;
    const float ozp = (float)out_zp_p[0];
    const int col = lane & 15;
    const int rgrp = lane >> 4;
#pragma unroll
    for (int ni = 0; ni < 4; ++ni) {
        const int n = n0 + wc * 64 + ni * 16 + col;
        const float bv = bias_f[n];
#pragma unroll
        for (int mi = 0; mi < 4; ++mi) {
#pragma unroll
            for (int j = 0; j < 4; ++j) {
                const int m = m0 + wr * 64 + mi * 16 + rgrp * 4 + j;
                float v = acc[mi][ni][j] + bv;
                float q = rintf(v * out_inv) + ozp;
                q = fminf(fmaxf(q, -128.0f), 127.0f);
                out[(size_t)m * N_DIM + n] = (q - ozp) * out_s;
            }
        }
    }
}

extern "C" void kernel_launch(void* const* d_in, const int* in_sizes, int n_in,
                              void* d_out, int out_size, void* d_ws, size_t ws_size,
                              hipStream_t stream) {
    const float* x          = (const float*)d_in[0];
    const int*   w_q        = (const int*)d_in[1];
    const float* w_scale    = (const float*)d_in[2];
    const int*   w_zp       = (const int*)d_in[3];
    const int*   bias_q     = (const int*)d_in[4];
    const float* bias_scale = (const float*)d_in[5];
    const float* in_scale   = (const float*)d_in[6];
    const int*   in_zp      = (const int*)d_in[7];
    const float* out_scale  = (const float*)d_in[8];
    const int*   out_zp     = (const int*)d_in[9];

    const size_t xq_bytes = (size_t)M_DIM * K_DIM * sizeof(__hip_bfloat16);  // 134 MB
    const size_t wb_bytes = (size_t)N_DIM * K_DIM * sizeof(__hip_bfloat16);  // 2 MB
    const size_t need = xq_bytes + wb_bytes + (size_t)N_DIM * sizeof(float);

    const int grid = (M_DIM / BM) * (N_DIM / BN);   // 4096

    if (ws_size >= need) {
        __hip_bfloat16* Xq = (__hip_bfloat16*)d_ws;
        __hip_bfloat16* Wb = (__hip_bfloat16*)((char*)d_ws + xq_bytes);
        float* bias_f = (float*)((char*)d_ws + xq_bytes + wb_bytes);

        prep_kernel<<<N_DIM, 256, 0, stream>>>(w_q, w_scale, w_zp, bias_q, bias_scale, Wb, bias_f);
        prep_x_kernel<<<(M_DIM * (size_t)K_DIM) / (256 * 8), 256, 0, stream>>>(x, in_scale, in_zp, Xq);
        gemm_lds_kernel<<<grid, 256, 0, stream>>>(Xq, Wb, bias_f, out_scale, out_zp, (float*)d_out);
    } else {
        __hip_bfloat16* Wb = (__hip_bfloat16*)d_ws;
        float* bias_f = (float*)((char*)d_ws + wb_bytes);

        prep_kernel<<<N_DIM, 256, 0, stream>>>(w_q, w_scale, w_zp, bias_q, bias_scale, Wb, bias_f);
        gemm_fused_kernel<<<grid, 256, 0, stream>>>(x, Wb, bias_f, in_scale, in_zp,
                                                    out_scale, out_zp, (float*)d_out);
    }
}

// Round 3
// 309.608 us; speedup vs baseline: 1.1876x; 1.0358x over previous
//
#include <hip/hip_runtime.h>
#include <hip/hip_bf16.h>

// Problem constants (B=8, S=8192, K=1024, N=1024, G=128)
#define M_DIM 65536
#define K_DIM 1024
#define N_DIM 1024
#define NGRP  8

// 256x256 deep-pipelined GEMM geometry
#define G_BM 256
#define G_BN 256
#define G_BK 32
#define G_NKT (K_DIM / G_BK)   // 32
#define NBUF 4                  // 4-deep LDS pipeline, 128 KiB total

// fallback geometry (round-1 fused kernel)
#define FB_BM 128
#define FB_BN 128
#define FB_BK 32
#define FB_NKT (K_DIM / FB_BK)

typedef float f32x4 __attribute__((ext_vector_type(4)));
typedef __bf16 bf16x8 __attribute__((ext_vector_type(8)));

// ---------------- prep: dequant W -> bf16 [N][K], bias -> f32 ----------------
__global__ void prep_kernel(const int* __restrict__ w_q,
                            const float* __restrict__ w_scale,
                            const int* __restrict__ w_zp,
                            const int* __restrict__ bias_q,
                            const float* __restrict__ bias_scale,
                            __hip_bfloat16* __restrict__ Wb,
                            float* __restrict__ bias_f) {
    const int n = blockIdx.x;       // 0..1023
    const int t = threadIdx.x;      // 0..255
    const int k0 = t * 4;
    const int g = k0 >> 7;          // group of 128
    const float s  = w_scale[n * NGRP + g];
    const float zp = (float)w_zp[n * NGRP + g];
    const int4 wq = *reinterpret_cast<const int4*>(w_q + (size_t)n * K_DIM + k0);
    union { ushort4 u; __hip_bfloat16 h[4]; } pk;
    pk.h[0] = __float2bfloat16(((float)wq.x - zp) * s);
    pk.h[1] = __float2bfloat16(((float)wq.y - zp) * s);
    pk.h[2] = __float2bfloat16(((float)wq.z - zp) * s);
    pk.h[3] = __float2bfloat16(((float)wq.w - zp) * s);
    *reinterpret_cast<ushort4*>(Wb + (size_t)n * K_DIM + k0) = pk.u;
    if (t == 0) bias_f[n] = ((float)bias_q[n] - 128.0f) * bias_scale[n];
}

// ---------------- prep: fake-quant x -> bf16 [M][K] ----------------
__global__ __launch_bounds__(256) void prep_x_kernel(
    const float* __restrict__ x,
    const float* __restrict__ in_scale_p, const int* __restrict__ in_zp_p,
    __hip_bfloat16* __restrict__ Xq)
{
    const float s = in_scale_p[0];
    const float inv = 1.0f / s;
    const float zp = (float)in_zp_p[0];
    const size_t i = ((size_t)blockIdx.x * 256 + threadIdx.x) * 8;
    const float4 v0 = *reinterpret_cast<const float4*>(x + i);
    const float4 v1 = *reinterpret_cast<const float4*>(x + i + 4);
    float vv[8] = {v0.x, v0.y, v0.z, v0.w, v1.x, v1.y, v1.z, v1.w};
    union { uint4 u; __hip_bfloat16 h[8]; } pk;
#pragma unroll
    for (int e = 0; e < 8; ++e) {
        float q = rintf(vv[e] * inv) + zp;       // RNE matches jnp.round
        q = fminf(fmaxf(q, -128.0f), 127.0f);
        pk.h[e] = __float2bfloat16((q - zp) * s);
    }
    *reinterpret_cast<uint4*>(Xq + i) = pk.u;
}

// ---------------- 256x256 deep-pipelined GEMM: counted vmcnt, raw barriers ----------------
__global__ __launch_bounds__(512, 2) void gemm256_kernel(
    const __hip_bfloat16* __restrict__ Xq,
    const __hip_bfloat16* __restrict__ Wb,
    const float* __restrict__ bias_f,
    const float* __restrict__ out_scale_p, const int* __restrict__ out_zp_p,
    float* __restrict__ out)
{
    __shared__ __align__(16) __hip_bfloat16 As[NBUF][G_BM * G_BK];  // 4 x 16 KiB
    __shared__ __align__(16) __hip_bfloat16 Bs[NBUF][G_BN * G_BK];  // 4 x 16 KiB

    const int t = threadIdx.x;
    // bijective XCD swizzle: grid=1024, 8 XCDs, 128 blocks/XCD.
    // consecutive bids share the A panel (mt) across nt=0..3.
    const int bid = (blockIdx.x & 7) * 128 + (blockIdx.x >> 3);
    const int nt = bid & 3;
    const int mt = bid >> 2;
    const int m0 = mt * G_BM;
    const int n0 = nt * G_BN;

    const int wid = t >> 6;
    const int lane = t & 63;
    const int wr = wid >> 2, wc = wid & 3;     // 2x4 waves, each owns 128x64 output
    const int lrow = lane & 15;
    const int kslot = lane >> 4;               // logical k-chunk (8 bf16)
    const int koff = ((kslot ^ ((lrow >> 1) & 3)) << 4);  // swizzled phys byte offset

    const __hip_bfloat16* Abase = Xq + (size_t)m0 * K_DIM;
    const __hip_bfloat16* Bbase = Wb + (size_t)n0 * K_DIM;

    // stage one 256x32 bf16 tile (16 KiB) via global_load_lds, pre-swizzled source.
    // 512 threads x 2 chunks x 16 B. dst is wave-uniform base; lane lands at +lane*16.
    auto stage = [&](const __hip_bfloat16* src0, __hip_bfloat16* ldsbuf, int kt) {
        const int k0 = kt * G_BK;
#pragma unroll
        for (int j = 0; j < 2; ++j) {
            const int c = j * 512 + t;                 // 16B chunk id, 0..1023
            const int r = c >> 2;                      // LDS row (64 B rows, 4 chunks)
            const int sl = (c & 3) ^ ((r >> 1) & 3);   // logical k-slot at this phys slot
            const __hip_bfloat16* src = src0 + (size_t)r * K_DIM + k0 + sl * 8;
            __builtin_amdgcn_global_load_lds(
                (const __attribute__((address_space(1))) void*)src,
                (__attribute__((address_space(3))) void*)((char*)ldsbuf + j * 8192 + wid * 1024),
                16, 0, 0);
        }
    };

    f32x4 acc[8][4];
#pragma unroll
    for (int mi = 0; mi < 8; ++mi)
#pragma unroll
        for (int ni = 0; ni < 4; ++ni)
            acc[mi][ni] = (f32x4){0.f, 0.f, 0.f, 0.f};

    // prologue: prefetch tiles 0,1,2  (12 outstanding loads/thread)
#pragma unroll
    for (int p = 0; p < 3; ++p) {
        stage(Abase, &As[p][0], p);
        stage(Bbase, &Bs[p][0], p);
    }

    for (int tk = 0; tk < G_NKT; ++tk) {
        const int buf = tk & 3;
        __builtin_amdgcn_sched_barrier(0);
        // counted wait: tile tk's 4 loads (oldest) retired; deeper prefetch stays in flight
        if (tk < G_NKT - 2)       asm volatile("s_waitcnt vmcnt(8)" ::: "memory");
        else if (tk == G_NKT - 2) asm volatile("s_waitcnt vmcnt(4)" ::: "memory");
        else                      asm volatile("s_waitcnt vmcnt(0)" ::: "memory");
        __builtin_amdgcn_s_barrier();
        __builtin_amdgcn_sched_barrier(0);

        // issue prefetch for tile tk+3 into buf (tk+3)&3 (last read at iter tk-1; safe)
        if (tk + 3 < G_NKT) {
            stage(Abase, &As[(tk + 3) & 3][0], tk + 3);
            stage(Bbase, &Bs[(tk + 3) & 3][0], tk + 3);
        }

        const char* Ab = (const char*)&As[buf][0];
        const char* Bb = (const char*)&Bs[buf][0];
        bf16x8 af[8], bfr[4];
#pragma unroll
        for (int mi = 0; mi < 8; ++mi) {
            const int row = wr * 128 + mi * 16 + lrow;
            af[mi] = *reinterpret_cast<const bf16x8*>(Ab + row * 64 + koff);
        }
#pragma unroll
        for (int ni = 0; ni < 4; ++ni) {
            const int row = wc * 64 + ni * 16 + lrow;
            bfr[ni] = *reinterpret_cast<const bf16x8*>(Bb + row * 64 + koff);
        }
        __builtin_amdgcn_s_setprio(1);
#pragma unroll
        for (int mi = 0; mi < 8; ++mi)
#pragma unroll
            for (int ni = 0; ni < 4; ++ni)
                acc[mi][ni] = __builtin_amdgcn_mfma_f32_16x16x32_bf16(af[mi], bfr[ni], acc[mi][ni], 0, 0, 0);
        __builtin_amdgcn_s_setprio(0);
    }

    // ---- epilogue: bias + output fake-quant ----
    const float out_s = out_scale_p[0];
    const float out_inv = 1.0f / out_s;
    const float ozp = (float)out_zp_p[0];
    const int col = lane & 15;
    const int rgrp = lane >> 4;
#pragma unroll
    for (int ni = 0; ni < 4; ++ni) {
        const int n = n0 + wc * 64 + ni * 16 + col;
        const float bv = bias_f[n];
#pragma unroll
        for (int mi = 0; mi < 8; ++mi) {
#pragma unroll
            for (int j = 0; j < 4; ++j) {
                const int m = m0 + wr * 128 + mi * 16 + rgrp * 4 + j;
                float v = acc[mi][ni][j] + bv;
                float q = rintf(v * out_inv) + ozp;
                q = fminf(fmaxf(q, -128.0f), 127.0f);
                out[(size_t)m * N_DIM + n] = (q - ozp) * out_s;
            }
        }
    }
}

// ---------------- fallback (round-1): fused quant in A-staging, f32 x ----------------
__global__ __launch_bounds__(256) void gemm_fused_kernel(
    const float* __restrict__ x,
    const __hip_bfloat16* __restrict__ Wb,
    const float* __restrict__ bias_f,
    const float* __restrict__ in_scale_p, const int* __restrict__ in_zp_p,
    const float* __restrict__ out_scale_p, const int* __restrict__ out_zp_p,
    float* __restrict__ out)
{
    __shared__ __align__(16) __hip_bfloat16 As[2][FB_BM][FB_BK];
    __shared__ __align__(16) __hip_bfloat16 Bs[2][FB_BN][FB_BK];

    const int t = threadIdx.x;
    const int bid = blockIdx.x;
    const int nt = bid & 7;
    const int mt = bid >> 3;
    const int m0 = mt * FB_BM;
    const int n0 = nt * FB_BN;

    const int wid = t >> 6;
    const int lane = t & 63;
    const int wr = wid >> 1, wc = wid & 1;
    const int lrow = lane & 15;
    const int kslot = lane >> 4;

    const float in_s = in_scale_p[0];
    const float in_inv = 1.0f / in_s;
    const float izp = (float)in_zp_p[0];

    auto stageB = [&](int b, int kt) {
        const int k0 = kt * FB_BK;
#pragma unroll
        for (int j = 0; j < 2; ++j) {
            const int c = (wid * 2 + j) * 64 + lane;
            const int row = c >> 2;
            const int slot = c & 3;
            const __hip_bfloat16* src = Wb + (size_t)(n0 + row) * K_DIM + k0 + slot * 8;
            __builtin_amdgcn_global_load_lds(
                (const __attribute__((address_space(1))) void*)src,
                (__attribute__((address_space(3))) void*)((char*)&Bs[b][0][0] + (wid * 2 + j) * 1024),
                16, 0, 0);
        }
    };
    auto stageA = [&](int b, int kt) {
        const int k0 = kt * FB_BK;
#pragma unroll
        for (int i = 0; i < 4; ++i) {
            const int c = t + 256 * i;
            const int row = c >> 3;
            const int slot = c & 7;
            const float4 v = *reinterpret_cast<const float4*>(
                x + (size_t)(m0 + row) * K_DIM + k0 + slot * 4);
            float vv[4] = {v.x, v.y, v.z, v.w};
            union { ushort4 u; __hip_bfloat16 h[4]; } pk;
#pragma unroll
            for (int e = 0; e < 4; ++e) {
                float q = rintf(vv[e] * in_inv) + izp;
                q = fminf(fmaxf(q, -128.0f), 127.0f);
                pk.h[e] = __float2bfloat16((q - izp) * in_s);
            }
            *reinterpret_cast<ushort4*>(&As[b][row][slot * 4]) = pk.u;
        }
    };

    f32x4 acc[4][4];
#pragma unroll
    for (int mi = 0; mi < 4; ++mi)
#pragma unroll
        for (int ni = 0; ni < 4; ++ni)
            acc[mi][ni] = (f32x4){0.f, 0.f, 0.f, 0.f};

    stageB(0, 0);
    stageA(0, 0);
    __syncthreads();

    for (int kt = 0; kt < FB_NKT; ++kt) {
        const int buf = kt & 1;
        if (kt + 1 < FB_NKT) {
            stageB(buf ^ 1, kt + 1);
            stageA(buf ^ 1, kt + 1);
        }
        bf16x8 af[4], bfr[4];
#pragma unroll
        for (int mi = 0; mi < 4; ++mi)
            af[mi] = *reinterpret_cast<const bf16x8*>(&As[buf][wr * 64 + mi * 16 + lrow][kslot * 8]);
#pragma unroll
        for (int ni = 0; ni < 4; ++ni)
            bfr[ni] = *reinterpret_cast<const bf16x8*>(&Bs[buf][wc * 64 + ni * 16 + lrow][kslot * 8]);
#pragma unroll
        for (int mi = 0; mi < 4; ++mi)
#pragma unroll
            for (int ni = 0; ni < 4; ++ni)
                acc[mi][ni] = __builtin_amdgcn_mfma_f32_16x16x32_bf16(af[mi], bfr[ni], acc[mi][ni], 0, 0, 0);
        __syncthreads();
    }

    const float out_s = out_scale_p[0];
    const float out_inv = 1.0f / out_s;
    const float ozp = (float)out_zp_p[0];
    const int col = lane & 15;
    const int rgrp = lane >> 4;
#pragma unroll
    for (int ni = 0; ni < 4; ++ni) {
        const int n = n0 + wc * 64 + ni * 16 + col;
        const float bv = bias_f[n];
#pragma unroll
        for (int mi = 0; mi < 4; ++mi) {
#pragma unroll
            for (int j = 0; j < 4; ++j) {
                const int m = m0 + wr * 64 + mi * 16 + rgrp * 4 + j;
                float v = acc[mi][ni][j] + bv;
                float q = rintf(v * out_inv) + ozp;
                q = fminf(fmaxf(q, -128.0f), 127.0f);
                out[(size_t)m * N_DIM + n] = (q - ozp) * out_s;
            }
        }
    }
}

extern "C" void kernel_launch(void* const* d_in, const int* in_sizes, int n_in,
                              void* d_out, int out_size, void* d_ws, size_t ws_size,
                              hipStream_t stream) {
    const float* x          = (const float*)d_in[0];
    const int*   w_q        = (const int*)d_in[1];
    const float* w_scale    = (const float*)d_in[2];
    const int*   w_zp       = (const int*)d_in[3];
    const int*   bias_q     = (const int*)d_in[4];
    const float* bias_scale = (const float*)d_in[5];
    const float* in_scale   = (const float*)d_in[6];
    const int*   in_zp      = (const int*)d_in[7];
    const float* out_scale  = (const float*)d_in[8];
    const int*   out_zp     = (const int*)d_in[9];

    const size_t xq_bytes = (size_t)M_DIM * K_DIM * sizeof(__hip_bfloat16);  // 134 MB
    const size_t wb_bytes = (size_t)N_DIM * K_DIM * sizeof(__hip_bfloat16);  // 2 MB
    const size_t need = xq_bytes + wb_bytes + (size_t)N_DIM * sizeof(float);

    if (ws_size >= need) {
        __hip_bfloat16* Xq = (__hip_bfloat16*)d_ws;
        __hip_bfloat16* Wb = (__hip_bfloat16*)((char*)d_ws + xq_bytes);
        float* bias_f = (float*)((char*)d_ws + xq_bytes + wb_bytes);

        prep_kernel<<<N_DIM, 256, 0, stream>>>(w_q, w_scale, w_zp, bias_q, bias_scale, Wb, bias_f);
        prep_x_kernel<<<(M_DIM * (size_t)K_DIM) / (256 * 8), 256, 0, stream>>>(x, in_scale, in_zp, Xq);

        const int grid = (M_DIM / G_BM) * (N_DIM / G_BN);   // 256 * 4 = 1024
        gemm256_kernel<<<grid, 512, 0, stream>>>(Xq, Wb, bias_f, out_scale, out_zp, (float*)d_out);
    } else {
        __hip_bfloat16* Wb = (__hip_bfloat16*)d_ws;
        float* bias_f = (float*)((char*)d_ws + wb_bytes);

        prep_kernel<<<N_DIM, 256, 0, stream>>>(w_q, w_scale, w_zp, bias_q, bias_scale, Wb, bias_f);
        const int grid = (M_DIM / FB_BM) * (N_DIM / FB_BN);
        gemm_fused_kernel<<<grid, 256, 0, stream>>>(x, Wb, bias_f, in_scale, in_zp,
                                                    out_scale, out_zp, (float*)d_out);
    }
}

// Round 5
// 261.013 us; speedup vs baseline: 1.4087x; 1.1862x over previous
//
#include <hip/hip_runtime.h>
#include <hip/hip_bf16.h>

// Problem constants (B=8, S=8192, K=1024, N=1024, G=128)
#define M_DIM 65536
#define K_DIM 1024
#define N_DIM 1024
#define NGRP  8

// 256x256 8-phase GEMM geometry (m201 template)
#define G_BM 256
#define G_BN 256
#define NKT64 (K_DIM / 64)      // 16 K-tiles of 64
#define NIT   (K_DIM / 128)     // 8 iterations (2 K-tiles each)

// fallback geometry (round-1 fused kernel)
#define FB_BM 128
#define FB_BN 128
#define FB_BK 32
#define FB_NKT (K_DIM / FB_BK)

typedef float f32x4 __attribute__((ext_vector_type(4)));
typedef __bf16 bf16x8 __attribute__((ext_vector_type(8)));

// ---------------- prep: dequant W -> bf16 [N][K], bias -> f32 ----------------
__global__ void prep_kernel(const int* __restrict__ w_q,
                            const float* __restrict__ w_scale,
                            const int* __restrict__ w_zp,
                            const int* __restrict__ bias_q,
                            const float* __restrict__ bias_scale,
                            __hip_bfloat16* __restrict__ Wb,
                            float* __restrict__ bias_f) {
    const int n = blockIdx.x;       // 0..1023
    const int t = threadIdx.x;      // 0..255
    const int k0 = t * 4;
    const int g = k0 >> 7;          // group of 128
    const float s  = w_scale[n * NGRP + g];
    const float zp = (float)w_zp[n * NGRP + g];
    const int4 wq = *reinterpret_cast<const int4*>(w_q + (size_t)n * K_DIM + k0);
    union { ushort4 u; __hip_bfloat16 h[4]; } pk;
    pk.h[0] = __float2bfloat16(((float)wq.x - zp) * s);
    pk.h[1] = __float2bfloat16(((float)wq.y - zp) * s);
    pk.h[2] = __float2bfloat16(((float)wq.z - zp) * s);
    pk.h[3] = __float2bfloat16(((float)wq.w - zp) * s);
    *reinterpret_cast<ushort4*>(Wb + (size_t)n * K_DIM + k0) = pk.u;
    if (t == 0) bias_f[n] = ((float)bias_q[n] - 128.0f) * bias_scale[n];
}

// ---------------- prep: fake-quant x -> bf16 [M][K] ----------------
__global__ __launch_bounds__(256) void prep_x_kernel(
    const float* __restrict__ x,
    const float* __restrict__ in_scale_p, const int* __restrict__ in_zp_p,
    __hip_bfloat16* __restrict__ Xq)
{
    const float s = in_scale_p[0];
    const float inv = 1.0f / s;
    const float zp = (float)in_zp_p[0];
    const size_t i = ((size_t)blockIdx.x * 256 + threadIdx.x) * 8;
    const float4 v0 = *reinterpret_cast<const float4*>(x + i);
    const float4 v1 = *reinterpret_cast<const float4*>(x + i + 4);
    float vv[8] = {v0.x, v0.y, v0.z, v0.w, v1.x, v1.y, v1.z, v1.w};
    union { uint4 u; __hip_bfloat16 h[8]; } pk;
#pragma unroll
    for (int e = 0; e < 8; ++e) {
        float q = rintf(vv[e] * inv) + zp;       // RNE matches jnp.round
        q = fminf(fmaxf(q, -128.0f), 127.0f);
        pk.h[e] = __float2bfloat16((q - zp) * s);
    }
    *reinterpret_cast<uint4*>(Xq + i) = pk.u;
}

// ---------------- 256x256 8-phase GEMM (m201 template, slot ring) ----------------
// LDS: 8 slots x 16 KiB. s0=A(2it,kk0) s1=B(2it,kk0) s2=A(2it,kk1) s3=B(2it,kk1)
//      s4=A(2it+1,kk0) s5=B(2it+1,kk0) s6=A(2it+1,kk1) s7=B(2it+1,kk1)
// Phase p's ds_reads are protected by phase p-1's {vmcnt wait; s_barrier}:
// main-loop vmcnt(6) leaves only the newest 3 stages outstanding, and every
// read is of a slot staged 5-6 phases back. WAR: a slot is restaged only
// after its last read's lgkmcnt(0)+closing-barrier.
// Prologue: 6 stages -> vmcnt(8) retires s0,s1 -> barrier.
// Tail (peeled last iter): waits {6,6,4,4,0,0,0,0} retire s3,s4,s5,s6,s7
// ahead of their reads (stages stop, so vmcnt(6) would stop retiring).
__global__ __launch_bounds__(512, 2) void gemm256_8ph_kernel(
    const __hip_bfloat16* __restrict__ Xq,
    const __hip_bfloat16* __restrict__ Wb,
    const float* __restrict__ bias_f,
    const float* __restrict__ out_scale_p, const int* __restrict__ out_zp_p,
    float* __restrict__ out)
{
    __shared__ __align__(16) __hip_bfloat16 LDS[8][8192];   // 128 KiB

    const int t = threadIdx.x;
    // bijective XCD swizzle: grid=1024, 8 XCDs, 128 blocks/XCD
    const int bid = (blockIdx.x & 7) * 128 + (blockIdx.x >> 3);
    const int nt = bid & 3;
    const int mt = bid >> 2;
    const int m0 = mt * G_BM;
    const int n0 = nt * G_BN;

    const int wid = t >> 6;
    const int lane = t & 63;
    const int wr = wid >> 2, wc = wid & 3;     // 2x4 waves, each owns 128x64 output
    const int lrow = lane & 15;
    const int kslot = lane >> 4;               // k-chunk (8 bf16) within 32-k slot
    const int koff = ((kslot ^ ((lrow >> 1) & 3)) << 4);
    const int widoff = wid * 1024;

    char* ldsb = (char*)&LDS[0][0];
    const __hip_bfloat16* Abase = Xq + (size_t)m0 * K_DIM;
    const __hip_bfloat16* Bbase = Wb + (size_t)n0 * K_DIM;

    // stage one half-tile slot (16 KiB = 256 rows x 32 k) via global_load_lds,
    // pre-swizzled source (both-sides rule; verified 0 conflicts r2/r3)
    auto stage = [&](int slot, const __hip_bfloat16* panel, int ktile, int kk) {
        const int k0 = ktile * 64 + kk * 32;
#pragma unroll
        for (int j = 0; j < 2; ++j) {
            const int c = j * 512 + t;                 // 16B chunk id 0..1023
            const int r = c >> 2;                      // row 0..255
            const int sl = (c & 3) ^ ((r >> 1) & 3);   // logical k-slot at this phys slot
            const __hip_bfloat16* src = panel + (size_t)r * K_DIM + k0 + sl * 8;
            __builtin_amdgcn_global_load_lds(
                (const __attribute__((address_space(1))) void*)src,
                (__attribute__((address_space(3))) void*)(ldsb + slot * 16384 + j * 8192 + widoff),
                16, 0, 0);
        }
    };

    bf16x8 af[4], bfr[4];
    auto rdA = [&](int slot, int mh) {
        const char* base = ldsb + slot * 16384;
#pragma unroll
        for (int i = 0; i < 4; ++i) {
            const int row = wr * 128 + (mh * 4 + i) * 16 + lrow;
            af[i] = *reinterpret_cast<const bf16x8*>(base + row * 64 + koff);
        }
    };
    auto rdB = [&](int slot) {
        const char* base = ldsb + slot * 16384;
#pragma unroll
        for (int i = 0; i < 4; ++i) {
            const int row = wc * 64 + i * 16 + lrow;
            bfr[i] = *reinterpret_cast<const bf16x8*>(base + row * 64 + koff);
        }
    };

    f32x4 acc[8][4];
#pragma unroll
    for (int mi = 0; mi < 8; ++mi)
#pragma unroll
        for (int ni = 0; ni < 4; ++ni)
            acc[mi][ni] = (f32x4){0.f, 0.f, 0.f, 0.f};

// one phase: {ds_reads | 1 stage | vmcnt(WN) | barrier | lgkmcnt(0) | 16 MFMA | barrier}
#define PHASE(RD, STG, WN, MH)                                                \
    do {                                                                      \
        RD;                                                                   \
        STG;                                                                  \
        asm volatile("s_waitcnt vmcnt(" #WN ")" ::: "memory");                \
        __builtin_amdgcn_s_barrier();                                         \
        asm volatile("s_waitcnt lgkmcnt(0)" ::: "memory");                    \
        __builtin_amdgcn_sched_barrier(0);                                    \
        __builtin_amdgcn_s_setprio(1);                                        \
        _Pragma("unroll")                                                     \
        for (int mi = 0; mi < 4; ++mi)                                        \
            _Pragma("unroll")                                                 \
            for (int ni = 0; ni < 4; ++ni)                                    \
                acc[(MH) * 4 + mi][ni] = __builtin_amdgcn_mfma_f32_16x16x32_bf16( \
                    af[mi], bfr[ni], acc[(MH) * 4 + mi][ni], 0, 0, 0);        \
        __builtin_amdgcn_s_setprio(0);                                        \
        __builtin_amdgcn_s_barrier();                                         \
        __builtin_amdgcn_sched_barrier(0);                                    \
    } while (0)

    // prologue: stage slots 0..5, then retire s0,s1 before ph0's reads
    stage(0, Abase, 0, 0);
    stage(1, Bbase, 0, 0);
    stage(2, Abase, 0, 1);
    stage(3, Bbase, 0, 1);
    stage(4, Abase, 1, 0);
    stage(5, Bbase, 1, 0);
    asm volatile("s_waitcnt vmcnt(8)" ::: "memory");
    __builtin_amdgcn_s_barrier();
    __builtin_amdgcn_sched_barrier(0);

#pragma unroll 1
    for (int it = 0; it < NIT - 1; ++it) {
        const int tA = 2 * it + 1;       // <= 13
        const int tB = 2 * it + 2;       // <= 14
        const int tC = 2 * it + 3;       // <= 15

        PHASE(rdB(1); rdA(0, 0), stage(6, Abase, tA, 1), 6, 0);
        PHASE(rdA(0, 1),         stage(7, Bbase, tA, 1), 6, 1);
        PHASE(rdB(3); rdA(2, 0), stage(0, Abase, tB, 0), 6, 0);
        PHASE(rdA(2, 1),         stage(1, Bbase, tB, 0), 6, 1);
        PHASE(rdB(5); rdA(4, 0), stage(2, Abase, tB, 1), 6, 0);
        PHASE(rdA(4, 1),         stage(3, Bbase, tB, 1), 6, 1);
        PHASE(rdB(7); rdA(6, 0), stage(4, Abase, tC, 0), 6, 0);
        PHASE(rdA(6, 1),         stage(5, Bbase, tC, 0), 6, 1);
    }

    // peeled last iteration (tA = NKT64-1; no tB/tC stages): draining waits
    {
        const int tA = 2 * (NIT - 1) + 1;    // 15
        PHASE(rdB(1); rdA(0, 0), stage(6, Abase, tA, 1), 6, 0);
        PHASE(rdA(0, 1),         stage(7, Bbase, tA, 1), 6, 1);
        PHASE(rdB(3); rdA(2, 0), (void)0,                4, 0);
        PHASE(rdA(2, 1),         (void)0,                4, 1);
        PHASE(rdB(5); rdA(4, 0), (void)0,                0, 0);
        PHASE(rdA(4, 1),         (void)0,                0, 1);
        PHASE(rdB(7); rdA(6, 0), (void)0,                0, 0);
        PHASE(rdA(6, 1),         (void)0,                0, 1);
    }

#undef PHASE

    // ---- epilogue: bias + output fake-quant ----
    const float out_s = out_scale_p[0];
    const float out_inv = 1.0f / out_s;
    const float ozp = (float)out_zp_p[0];
    const int col = lane & 15;
    const int rgrp = lane >> 4;
#pragma unroll
    for (int ni = 0; ni < 4; ++ni) {
        const int n = n0 + wc * 64 + ni * 16 + col;
        const float bv = bias_f[n];
#pragma unroll
        for (int mi = 0; mi < 8; ++mi) {
#pragma unroll
            for (int j = 0; j < 4; ++j) {
                const int m = m0 + wr * 128 + mi * 16 + rgrp * 4 + j;
                float v = acc[mi][ni][j] + bv;
                float q = rintf(v * out_inv) + ozp;
                q = fminf(fmaxf(q, -128.0f), 127.0f);
                out[(size_t)m * N_DIM + n] = (q - ozp) * out_s;
            }
        }
    }
}

// ---------------- fallback (round-1): fused quant in A-staging, f32 x ----------------
__global__ __launch_bounds__(256) void gemm_fused_kernel(
    const float* __restrict__ x,
    const __hip_bfloat16* __restrict__ Wb,
    const float* __restrict__ bias_f,
    const float* __restrict__ in_scale_p, const int* __restrict__ in_zp_p,
    const float* __restrict__ out_scale_p, const int* __restrict__ out_zp_p,
    float* __restrict__ out)
{
    __shared__ __align__(16) __hip_bfloat16 As[2][FB_BM][FB_BK];
    __shared__ __align__(16) __hip_bfloat16 Bs[2][FB_BN][FB_BK];

    const int t = threadIdx.x;
    const int bid = blockIdx.x;
    const int nt = bid & 7;
    const int mt = bid >> 3;
    const int m0 = mt * FB_BM;
    const int n0 = nt * FB_BN;

    const int wid = t >> 6;
    const int lane = t & 63;
    const int wr = wid >> 1, wc = wid & 1;
    const int lrow = lane & 15;
    const int kslot = lane >> 4;

    const float in_s = in_scale_p[0];
    const float in_inv = 1.0f / in_s;
    const float izp = (float)in_zp_p[0];

    auto stageB = [&](int b, int kt) {
        const int k0 = kt * FB_BK;
#pragma unroll
        for (int j = 0; j < 2; ++j) {
            const int c = (wid * 2 + j) * 64 + lane;
            const int row = c >> 2;
            const int slot = c & 3;
            const __hip_bfloat16* src = Wb + (size_t)(n0 + row) * K_DIM + k0 + slot * 8;
            __builtin_amdgcn_global_load_lds(
                (const __attribute__((address_space(1))) void*)src,
                (__attribute__((address_space(3))) void*)((char*)&Bs[b][0][0] + (wid * 2 + j) * 1024),
                16, 0, 0);
        }
    };
    auto stageA = [&](int b, int kt) {
        const int k0 = kt * FB_BK;
#pragma unroll
        for (int i = 0; i < 4; ++i) {
            const int c = t + 256 * i;
            const int row = c >> 3;
            const int slot = c & 7;
            const float4 v = *reinterpret_cast<const float4*>(
                x + (size_t)(m0 + row) * K_DIM + k0 + slot * 4);
            float vv[4] = {v.x, v.y, v.z, v.w};
            union { ushort4 u; __hip_bfloat16 h[4]; } pk;
#pragma unroll
            for (int e = 0; e < 4; ++e) {
                float q = rintf(vv[e] * in_inv) + izp;
                q = fminf(fmaxf(q, -128.0f), 127.0f);
                pk.h[e] = __float2bfloat16((q - izp) * in_s);
            }
            *reinterpret_cast<ushort4*>(&As[b][row][slot * 4]) = pk.u;
        }
    };

    f32x4 acc[4][4];
#pragma unroll
    for (int mi = 0; mi < 4; ++mi)
#pragma unroll
        for (int ni = 0; ni < 4; ++ni)
            acc[mi][ni] = (f32x4){0.f, 0.f, 0.f, 0.f};

    stageB(0, 0);
    stageA(0, 0);
    __syncthreads();

    for (int kt = 0; kt < FB_NKT; ++kt) {
        const int buf = kt & 1;
        if (kt + 1 < FB_NKT) {
            stageB(buf ^ 1, kt + 1);
            stageA(buf ^ 1, kt + 1);
        }
        bf16x8 af[4], bfr[4];
#pragma unroll
        for (int mi = 0; mi < 4; ++mi)
            af[mi] = *reinterpret_cast<const bf16x8*>(&As[buf][wr * 64 + mi * 16 + lrow][kslot * 8]);
#pragma unroll
        for (int ni = 0; ni < 4; ++ni)
            bfr[ni] = *reinterpret_cast<const bf16x8*>(&Bs[buf][wc * 64 + ni * 16 + lrow][kslot * 8]);
#pragma unroll
        for (int mi = 0; mi < 4; ++mi)
#pragma unroll
            for (int ni = 0; ni < 4; ++ni)
                acc[mi][ni] = __builtin_amdgcn_mfma_f32_16x16x32_bf16(af[mi], bfr[ni], acc[mi][ni], 0, 0, 0);
        __syncthreads();
    }

    const float out_s = out_scale_p[0];
    const float out_inv = 1.0f / out_s;
    const float ozp = (float)out_zp_p[0];
    const int col = lane & 15;
    const int rgrp = lane >> 4;
#pragma unroll
    for (int ni = 0; ni < 4; ++ni) {
        const int n = n0 + wc * 64 + ni * 16 + col;
        const float bv = bias_f[n];
#pragma unroll
        for (int mi = 0; mi < 4; ++mi) {
#pragma unroll
            for (int j = 0; j < 4; ++j) {
                const int m = m0 + wr * 64 + mi * 16 + rgrp * 4 + j;
                float v = acc[mi][ni][j] + bv;
                float q = rintf(v * out_inv) + ozp;
                q = fminf(fmaxf(q, -128.0f), 127.0f);
                out[(size_t)m * N_DIM + n] = (q - ozp) * out_s;
            }
        }
    }
}

extern "C" void kernel_launch(void* const* d_in, const int* in_sizes, int n_in,
                              void* d_out, int out_size, void* d_ws, size_t ws_size,
                              hipStream_t stream) {
    const float* x          = (const float*)d_in[0];
    const int*   w_q        = (const int*)d_in[1];
    const float* w_scale    = (const float*)d_in[2];
    const int*   w_zp       = (const int*)d_in[3];
    const int*   bias_q     = (const int*)d_in[4];
    const float* bias_scale = (const float*)d_in[5];
    const float* in_scale   = (const float*)d_in[6];
    const int*   in_zp      = (const int*)d_in[7];
    const float* out_scale  = (const float*)d_in[8];
    const int*   out_zp     = (const int*)d_in[9];

    const size_t xq_bytes = (size_t)M_DIM * K_DIM * sizeof(__hip_bfloat16);  // 134 MB
    const size_t wb_bytes = (size_t)N_DIM * K_DIM * sizeof(__hip_bfloat16);  // 2 MB
    const size_t need = xq_bytes + wb_bytes + (size_t)N_DIM * sizeof(float);

    if (ws_size >= need) {
        __hip_bfloat16* Xq = (__hip_bfloat16*)d_ws;
        __hip_bfloat16* Wb = (__hip_bfloat16*)((char*)d_ws + xq_bytes);
        float* bias_f = (float*)((char*)d_ws + xq_bytes + wb_bytes);

        prep_kernel<<<N_DIM, 256, 0, stream>>>(w_q, w_scale, w_zp, bias_q, bias_scale, Wb, bias_f);
        prep_x_kernel<<<(M_DIM * (size_t)K_DIM) / (256 * 8), 256, 0, stream>>>(x, in_scale, in_zp, Xq);

        const int grid = (M_DIM / G_BM) * (N_DIM / G_BN);   // 256 * 4 = 1024
        gemm256_8ph_kernel<<<grid, 512, 0, stream>>>(Xq, Wb, bias_f, out_scale, out_zp, (float*)d_out);
    } else {
        __hip_bfloat16* Wb = (__hip_bfloat16*)d_ws;
        float* bias_f = (float*)((char*)d_ws + wb_bytes);

        prep_kernel<<<N_DIM, 256, 0, stream>>>(w_q, w_scale, w_zp, bias_q, bias_scale, Wb, bias_f);
        const int grid = (M_DIM / FB_BM) * (N_DIM / FB_BN);
        gemm_fused_kernel<<<grid, 256, 0, stream>>>(x, Wb, bias_f, in_scale, in_zp,
                                                    out_scale, out_zp, (float*)d_out);
    }
}